// Round 21
// baseline (1515.834 us; speedup 1.0000x reference)
//
#include <hip/hip_runtime.h>
#include <hip/hip_bf16.h>
#include <hip/hip_fp16.h>

#define N_NODES 100000
#define N_EDGES 400000
#define NB      4096
#define FAT     30
#define FBOND   11
#define HDIM    256
#define NLAY    5
#define CK      128

typedef short s8v  __attribute__((ext_vector_type(8)));
typedef float f32x4 __attribute__((ext_vector_type(4)));
typedef _Float16 f16x8 __attribute__((ext_vector_type(8)));
typedef unsigned int u32;

static __device__ __forceinline__ float sigmoidf_(float x){ return 1.0f/(1.0f+expf(-x)); }
static __device__ __forceinline__ float h2f_(short s){
  return __half2float(__ushort_as_half((unsigned short)s));
}
static __device__ __forceinline__ short f2h_(float f){
  return (short)__half_as_ushort(__float2half(f));
}
// packed fp16 ops via inline asm (avoids fp16/bf16 header overload ambiguity)
static __device__ __forceinline__ u32 pk_fma(u32 a, u32 b, u32 c){
  u32 r; asm("v_pk_fma_f16 %0, %1, %2, %3" : "=v"(r) : "v"(a), "v"(b), "v"(c)); return r;
}
static __device__ __forceinline__ u32 pk_add(u32 a, u32 b){
  u32 r; asm("v_pk_add_f16 %0, %1, %2" : "=v"(r) : "v"(a), "v"(b)); return r;
}
static __device__ __forceinline__ u32 pk_mul(u32 a, u32 b){
  u32 r; asm("v_pk_mul_f16 %0, %1, %2" : "=v"(r) : "v"(a), "v"(b)); return r;
}
static __device__ __forceinline__ u32 pk_max(u32 a, u32 b){
  u32 r; asm("v_pk_max_f16 %0, %1, %2" : "=v"(r) : "v"(a), "v"(b)); return r;
}

// ---------------- sentinel (ws too small diagnostic) ----------------
__global__ void sentinel_kernel(float* out, int n){
  int i = blockIdx.x*256 + threadIdx.x;
  if (i < n) out[i] = 12345.0f;
}

// ---------------- atom embedding: hb0 fp16 master ----------------
__global__ void atom_embed_kernel(const float* __restrict__ x, const float* __restrict__ W,
                                  const float* __restrict__ b, short* __restrict__ hb0){
  __shared__ float xs[8][FAT];
  int n0 = blockIdx.x * 8;
  int t = threadIdx.x;
  if (t < 8*FAT) xs[t/FAT][t%FAT] = x[(size_t)(n0 + t/FAT)*FAT + t%FAT];
  __syncthreads();
  int c = t;
  float acc[8];
  float bias = b[c];
  #pragma unroll
  for (int r=0;r<8;r++) acc[r]=bias;
  #pragma unroll
  for (int k=0;k<FAT;k++){
    float w = W[k*HDIM + c];
    #pragma unroll
    for (int r=0;r<8;r++) acc[r] += xs[r][k]*w;
  }
  #pragma unroll
  for (int r=0;r<8;r++)
    hb0[(size_t)(n0+r)*HDIM + c] = f2h_(acc[r]);
}

// ---------------- CSR build over dst ----------------
__global__ void count_kernel(const int* __restrict__ dst, int* __restrict__ counts, int E){
  int e = blockIdx.x*blockDim.x + threadIdx.x;
  if (e < E) atomicAdd(&counts[dst[e]], 1);
}

__global__ void scan_kernel(const int* __restrict__ counts, int* __restrict__ row_ptr, int n){
  __shared__ int part[1024];
  int t = threadIdx.x;
  int chunk = (n + 1023) >> 10;
  int s = t*chunk, e2 = min(s+chunk, n);
  int sum = 0;
  for (int i=s;i<e2;i++) sum += counts[i];
  part[t] = sum; __syncthreads();
  for (int off=1; off<1024; off<<=1){
    int v = (t>=off) ? part[t-off] : 0;
    __syncthreads();
    part[t] += v;
    __syncthreads();
  }
  int run = part[t]-sum;
  for (int i=s;i<e2;i++){ row_ptr[i]=run; run+=counts[i]; }
  if (e2==n && s<=n) row_ptr[n]=run;
}

__global__ void fill_kernel(const int* __restrict__ dst, int* __restrict__ cursor,
                            int* __restrict__ sorted_eid, int E){
  int e = blockIdx.x*blockDim.x + threadIdx.x;
  if (e < E){ int pos = atomicAdd(&cursor[dst[e]],1); sorted_eid[pos]=e; }
}

__global__ void segstart_kernel(const int* __restrict__ batch, int* __restrict__ segs, int n, int nb){
  int g = blockIdx.x*blockDim.x + threadIdx.x;
  if (g > nb) return;
  int lo=0, hi=n;
  while (lo<hi){ int mid=(lo+hi)>>1; if (batch[mid] < g) lo=mid+1; else hi=mid; }
  segs[g]=lo;
}

// ---------------- one-time edge reorder: linear src + broadcast-fp16 edge_attr ------
__global__ void reorder_kernel(const int* __restrict__ s_eid, const int* __restrict__ src,
                               const float* __restrict__ ea,
                               int* __restrict__ s_src, short* __restrict__ eah2, int E){
  int i = blockIdx.x*256 + threadIdx.x;
  if (i >= E) return;
  int eid = s_eid[i];
  s_src[i] = src[eid];
  const float* a = ea + (size_t)eid*FBOND;
  short* o = eah2 + (size_t)i*24;
  #pragma unroll
  for (int k=0;k<FBOND;k++){
    short hv = f2h_(a[k]);
    o[2*k]   = hv;
    o[2*k+1] = hv;
  }
  o[22] = 0; o[23] = 0;
}

// ---------------- pack bond weights/bias to fp16 ----------------
__global__ void bondpack_kernel(const float* __restrict__ bW, const float* __restrict__ bb,
                                short* __restrict__ bWh, short* __restrict__ bbh){
  int idx = blockIdx.x*256 + threadIdx.x;
  if (idx < FBOND*HDIM) bWh[idx] = f2h_(bW[idx]);
  if (idx < HDIM)       bbh[idx] = f2h_(bb[idx]);
}

// ---------------- pack weights into MFMA B-fragment layout, single fp16 -------------
__global__ void packB_kernel(const float* __restrict__ B, short* __restrict__ Bp, int K, int N){
  int idx = blockIdx.x*256 + threadIdx.x;
  if (idx >= K*N) return;
  int b    = idx & 7;
  int lane = (idx >> 3) & 63;
  int t2   = idx >> 9;
  int KT   = K >> 5;
  int kt   = t2 % KT, nt = t2 / KT;
  int k = kt*32 + ((lane>>4)<<3) + b;
  int n = nt*16 + (lane&15);
  Bp[idx] = f2h_(B[(size_t)k*N + n]);
}

// ---------------- pack LSTM [Wih|Whh]^T (K=768, N=1024) + bias, fp16 --------
__global__ void packWcat_kernel(const float* __restrict__ Wih, const float* __restrict__ Whh,
                                const float* __restrict__ bih, const float* __restrict__ bhh,
                                short* __restrict__ Wcp, float* __restrict__ bias_c){
  int idx = blockIdx.x*256 + threadIdx.x;
  if (idx < 1024) bias_c[idx] = bih[idx] + bhh[idx];
  if (idx >= 768*1024) return;
  int b    = idx & 7;
  int lane = (idx >> 3) & 63;
  int t2   = idx >> 9;
  const int KT = 24;
  int kt   = t2 % KT, nt = t2 / KT;
  int k = kt*32 + ((lane>>4)<<3) + b;
  int n = nt*16 + (lane&15);
  float w = (k < 512) ? Wih[(size_t)n*512 + k] : Whh[(size_t)n*256 + (k-512)];
  Wcp[idx] = f2h_(w);
}

// ---------------- fully fused GINE layer (fp16 master, packed-fp16 messages) --------
// 32 nodes/block, 512 threads. LDS 33.8 KB -> 4 blocks/CU (32 waves/CU, HW max).
// Working set (hb x2 + eah2 = 121 MB) is L3-resident so no cache thrash (r20
// evidence at 3 blocks); extra concurrency feeds the latency-bound gather stream.
// Epilogue re-reads own rows of hbin (L2-hot from phase 1) instead of LDS staging.
__launch_bounds__(512, 8)
__global__ void gine_layer_kernel(
    const short* __restrict__ hbin, short* __restrict__ hbout,
    const short* __restrict__ bWh, const short* __restrict__ bbh,
    const int* __restrict__ s_src, const short* __restrict__ eah2,
    const int* __restrict__ row_ptr, const float* __restrict__ eps, int layer,
    const short* __restrict__ B1p, const short* __restrict__ B2p,
    const float* __restrict__ sc1v, const float* __restrict__ sh1v,
    const float* __restrict__ sc2v, const float* __restrict__ sh2v){
  __shared__ short smem[16896];        // 33.8 KB -> 4 blocks/CU
  short* sZ  = smem;                   // [32][264] fp16
  short* sC1 = smem;                   // [32][520] fp16 (aliases z after GEMM1)
  float* sOut = (float*)smem;          // [32][264] fp32 (aliases c1 after GEMM2)
  int t = threadIdx.x;
  int lane = t & 63, wid = t >> 6;
  int lrow = lane & 15, lk8 = (lane>>4)<<3, drow0 = (lane>>4)<<2;
  int m0 = blockIdx.x * 32;
  int c0 = lane*4;

  // ---- phase 1: message pass, packed fp16 (inline-asm VOP3P) ----
  {
    u32 w2[FBOND][2];
    #pragma unroll
    for (int k=0;k<FBOND;k++){
      w2[k][0] = *(const u32*)&bWh[k*HDIM + c0];
      w2[k][1] = *(const u32*)&bWh[k*HDIM + c0 + 2];
    }
    u32 bbA = *(const u32*)&bbh[c0];
    u32 bbB = *(const u32*)&bbh[c0 + 2];
    unsigned short eh = (unsigned short)f2h_(1.0f + eps[layer]);
    u32 eps2 = ((u32)eh << 16) | eh;
    for (int nn=0; nn<4; ++nn){
      int nl = wid*4 + nn;
      int node = m0 + nl;
      short4 hself = *(const short4*)&hbin[(size_t)node*HDIM + c0];
      u32 hs0 = *(u32*)&hself.x;
      u32 hs1 = *(u32*)&hself.z;
      u32 acc0 = pk_mul(eps2, hs0);
      u32 acc1 = pk_mul(eps2, hs1);
      int s = row_ptr[node], e = row_ptr[node+1];
      u32 hc0 = 0u, hc1 = 0u;
      if (s < e){
        short4 g4 = *(const short4*)&hbin[(size_t)s_src[s]*HDIM + c0];
        hc0 = *(u32*)&g4.x; hc1 = *(u32*)&g4.z;
      }
      for (int idx=s; idx<e; idx++){
        u32 hn0 = hc0, hn1 = hc1;
        if (idx+1 < e){
          short4 g4 = *(const short4*)&hbin[(size_t)s_src[idx+1]*HDIM + c0];
          hn0 = *(u32*)&g4.x; hn1 = *(u32*)&g4.z;
        }
        const u32* ap = (const u32*)(eah2 + (size_t)idx*24);
        u32 e0 = bbA, e1 = bbB;
        #pragma unroll
        for (int k=0;k<FBOND;k++){
          u32 a = ap[k];
          e0 = pk_fma(a, w2[k][0], e0);
          e1 = pk_fma(a, w2[k][1], e1);
        }
        e0 = pk_max(pk_add(hc0, e0), 0u);
        e1 = pk_max(pk_add(hc1, e1), 0u);
        acc0 = pk_add(acc0, e0);
        acc1 = pk_add(acc1, e1);
        hc0 = hn0; hc1 = hn1;
      }
      short4 zz;
      *(u32*)&zz.x = acc0;
      *(u32*)&zz.z = acc1;
      *(short4*)&sZ[nl*264 + c0] = zz;
    }
  }
  __syncthreads();

  // ---- phase 2: GEMM1, wave computes c1 cols [wid*64, +64), rows 0..31 ----
  f32x4 acc1g[2][4];
  #pragma unroll
  for (int i=0;i<2;i++)
    #pragma unroll
    for (int j=0;j<4;j++) acc1g[i][j] = (f32x4){0.f,0.f,0.f,0.f};
  size_t b1base = (size_t)wid*16384 + lane*8;          // nt = wid*4+nf, KT=8
  for (int kt=0; kt<8; ++kt){
    f16x8 bv[4];
    #pragma unroll
    for (int nf=0;nf<4;nf++)
      bv[nf] = *(const f16x8*)(B1p + b1base + ((size_t)nf*8 + kt)*512);
    #pragma unroll
    for (int mf=0;mf<2;mf++){
      int rsh = (mf*16 + lrow)*264 + kt*32 + lk8;
      f16x8 a = *(const f16x8*)&sZ[rsh];
      #pragma unroll
      for (int nf=0;nf<4;nf++)
        acc1g[mf][nf] = __builtin_amdgcn_mfma_f32_16x16x32_f16(a, bv[nf], acc1g[mf][nf],0,0,0);
    }
  }
  __syncthreads();   // all waves done reading z

  // ---- phase 3: write c1 = relu(bn1(.)) fp16 into LDS ----
  #pragma unroll
  for (int nf=0;nf<4;nf++){
    int col = wid*64 + nf*16 + lrow;
    float scv = sc1v[col], shv = sh1v[col];
    #pragma unroll
    for (int mf=0;mf<2;mf++){
      int row = mf*16 + drow0;
      #pragma unroll
      for (int r=0;r<4;r++){
        float v = fmaxf(acc1g[mf][nf][r]*scv + shv, 0.f);
        sC1[(row+r)*520 + col] = f2h_(v);
      }
    }
  }
  __syncthreads();

  // ---- phase 4: GEMM2, wave computes out cols [wid*32, +32), K=512 ----
  f32x4 acc2[2][2];
  #pragma unroll
  for (int i=0;i<2;i++)
    #pragma unroll
    for (int j=0;j<2;j++) acc2[i][j] = (f32x4){0.f,0.f,0.f,0.f};
  size_t b2base = (size_t)wid*16384 + lane*8;          // nt2 = wid*2+nf, KT2=16
  for (int kt=0; kt<16; ++kt){
    f16x8 b0 = *(const f16x8*)(B2p + b2base + (size_t)kt*512);
    f16x8 b1 = *(const f16x8*)(B2p + b2base + (size_t)(16+kt)*512);
    #pragma unroll
    for (int mf=0;mf<2;mf++){
      int rsh = (mf*16 + lrow)*520 + kt*32 + lk8;
      f16x8 a = *(const f16x8*)&sC1[rsh];
      acc2[mf][0] = __builtin_amdgcn_mfma_f32_16x16x32_f16(a, b0, acc2[mf][0],0,0,0);
      acc2[mf][1] = __builtin_amdgcn_mfma_f32_16x16x32_f16(a, b1, acc2[mf][1],0,0,0);
    }
  }
  __syncthreads();   // all waves done reading c1

  // ---- phase 5a: stage relu(bn2(.)) fp32 into LDS (aliases c1) ----
  #pragma unroll
  for (int nf=0;nf<2;nf++){
    int col = wid*32 + nf*16 + lrow;
    float scv = sc2v[col], shv = sh2v[col];
    #pragma unroll
    for (int mf=0;mf<2;mf++){
      #pragma unroll
      for (int r=0;r<4;r++){
        int rr = mf*16 + drow0 + r;
        sOut[rr*264 + col] = fmaxf(acc2[mf][nf][r]*scv + shv, 0.f);
      }
    }
  }
  __syncthreads();

  // ---- phase 5b: coalesced hbout = fp16(out + h_old) (h_old re-read, L2-hot) ----
  {
    int row = t >> 4, cs = (t & 15) * 16;
    int grow = m0 + row;
    const float* op = &sOut[row*264 + cs];
    const short* hp = hbin + (size_t)grow*HDIM + cs;
    s8v h0 = *(const s8v*)(hp);
    s8v h1 = *(const s8v*)(hp + 8);
    s8v o0, o1;
    #pragma unroll
    for (int i=0;i<8;i++){
      o0[i] = f2h_(op[i]   + h2f_(h0[i]));
      o1[i] = f2h_(op[8+i] + h2f_(h1[i]));
    }
    short* mp = hbout + (size_t)grow*HDIM + cs;
    *(s8v*)(mp)     = o0;
    *(s8v*)(mp + 8) = o1;
  }
}

// ---------------- fp16 MFMA GEMM (LSTM gates), LDS-staged A ----------------
__launch_bounds__(256)
__global__ void gemm_mfma0(const short* __restrict__ Ap, const short* __restrict__ Bp,
                           int M, int N, int K,
                           const float* __restrict__ sh, float* __restrict__ Cf){
  __shared__ short As[2][64*72];
  int t    = threadIdx.x;
  int lane = t & 63;
  int wid  = t >> 6;
  int m0 = blockIdx.y * 64;
  int n0 = blockIdx.x * 128 + wid * 32;
  int lrow = lane & 15;
  int lk8  = (lane >> 4) << 3;
  int KT = K >> 5;
  int NT = K >> 6;

  f32x4 acc[4][2];
  #pragma unroll
  for (int i=0;i<4;i++)
    #pragma unroll
    for (int j=0;j<2;j++) acc[i][j] = (f32x4){0.f,0.f,0.f,0.f};

  int r0 = t >> 3, c8 = t & 7;
  int gr0 = min(m0 + r0,      M-1);
  int gr1 = min(m0 + r0 + 32, M-1);
  const short* pa0 = Ap + (size_t)gr0*K + c8*8;
  const short* pa1 = Ap + (size_t)gr1*K + c8*8;
  int wsh0 = r0*72 + c8*8;
  int wsh1 = (r0+32)*72 + c8*8;

  size_t boff = ((size_t)(n0 >> 4) * KT) * 512 + lane*8;

  s8v v0 = *(const s8v*)(pa0);
  s8v v1 = *(const s8v*)(pa1);
  *(s8v*)&As[0][wsh0] = v0;  *(s8v*)&As[0][wsh1] = v1;
  __syncthreads();

  for (int st=0; st<NT; ++st){
    int cur = st & 1;
    if (st+1 < NT){
      int ko = (st+1)*64;
      v0 = *(const s8v*)(pa0 + ko);
      v1 = *(const s8v*)(pa1 + ko);
    }
    #pragma unroll
    for (int ktl=0; ktl<2; ++ktl){
      int kt = st*2 + ktl;
      f16x8 b0 = *(const f16x8*)(Bp + boff + (size_t)kt*512);
      f16x8 b1 = *(const f16x8*)(Bp + boff + (size_t)(KT + kt)*512);
      int ksh = ktl*32 + lk8;
      #pragma unroll
      for (int mf=0; mf<4; ++mf){
        int rsh = (mf*16 + lrow)*72 + ksh;
        f16x8 a = *(const f16x8*)&As[cur][rsh];
        acc[mf][0] = __builtin_amdgcn_mfma_f32_16x16x32_f16(a, b0, acc[mf][0], 0,0,0);
        acc[mf][1] = __builtin_amdgcn_mfma_f32_16x16x32_f16(a, b1, acc[mf][1], 0,0,0);
      }
    }
    if (st+1 < NT){
      int nxt = cur ^ 1;
      *(s8v*)&As[nxt][wsh0] = v0;  *(s8v*)&As[nxt][wsh1] = v1;
    }
    __syncthreads();
  }

  int drow0 = (lane >> 4) * 4;
  #pragma unroll
  for (int nf=0; nf<2; nf++){
    int col = n0 + nf*16 + lrow;
    float shv = sh[col];
    #pragma unroll
    for (int mf=0; mf<4; mf++){
      #pragma unroll
      for (int r=0; r<4; r++){
        int row = m0 + mf*16 + drow0 + r;
        if (row < M) Cf[(size_t)row*N + col] = acc[mf][nf][r] + shv;
      }
    }
  }
}

// ---------------- BN fold ----------------
__global__ void fold_kernel(
  const float* __restrict__ b1,  const float* __restrict__ g1,  const float* __restrict__ bb1,
  const float* __restrict__ m1,  const float* __restrict__ v1,
  const float* __restrict__ b2,  const float* __restrict__ g2,  const float* __restrict__ bb2,
  const float* __restrict__ m2,  const float* __restrict__ v2,
  const float* __restrict__ cb1, const float* __restrict__ cg1, const float* __restrict__ cbb1,
  const float* __restrict__ cm1, const float* __restrict__ cv1,
  const float* __restrict__ cb2, const float* __restrict__ cg2, const float* __restrict__ cbb2,
  const float* __restrict__ cm2, const float* __restrict__ cv2,
  float* __restrict__ sc1, float* __restrict__ sh1,
  float* __restrict__ sc2, float* __restrict__ sh2,
  float* __restrict__ csc1, float* __restrict__ csh1,
  float* __restrict__ csc2, float* __restrict__ csh2){
  int idx = blockIdx.x*256 + threadIdx.x;
  const int n1 = NLAY*512, n2 = NLAY*256;
  if (idx < n1){
    float s = g1[idx]*rsqrtf(v1[idx]+1e-5f);
    sc1[idx]=s; sh1[idx]=(b1[idx]-m1[idx])*s + bb1[idx];
  } else if (idx < n1+n2){
    int i = idx-n1;
    float s = g2[i]*rsqrtf(v2[i]+1e-5f);
    sc2[i]=s; sh2[i]=(b2[i]-m2[i])*s + bb2[i];
  } else if (idx < n1+n2+256){
    int i = idx-n1-n2;
    float s = cg1[i]*rsqrtf(cv1[i]+1e-5f);
    csc1[i]=s; csh1[i]=(cb1[i]-cm1[i])*s + cbb1[i];
  } else if (idx < n1+n2+256+128){
    int i = idx-n1-n2-256;
    float s = cg2[i]*rsqrtf(cv2[i]+1e-5f);
    csc2[i]=s; csh2[i]=(cb2[i]-cm2[i])*s + cbb2[i];
  }
}

// ---------------- LSTM pointwise (writes q/hst fp32 + fp16 mirror) ----------------
__global__ void lstm_kernel(const float* __restrict__ gates, float* __restrict__ cst,
                            float* __restrict__ qs, short* __restrict__ qsh){
  int idx = blockIdx.x*256 + threadIdx.x;
  int b = idx >> 8, j = idx & 255;
  const float* g = &gates[(size_t)b*1024];
  float ig = sigmoidf_(g[j]);
  float fg = sigmoidf_(g[j+256]);
  float gg = tanhf(g[j+512]);
  float og = sigmoidf_(g[j+768]);
  float c  = fg*cst[idx] + ig*gg;
  float hv = og*tanhf(c);
  cst[idx] = c;
  size_t base = (size_t)b*768;
  qs[base + j]       = hv;
  qs[base + 512 + j] = hv;
  short hh = f2h_(hv);
  qsh[base + j] = hh;
  qsh[base + 512 + j] = hh;
}

// ---------------- fused attention (fp16 h): ener + softmax + weighted r ----------------
__global__ void attn_fused_kernel(const short* __restrict__ hb, float* __restrict__ qs,
                                  short* __restrict__ qsh, const int* __restrict__ segs){
  __shared__ float en[CK];
  __shared__ float red[256];
  __shared__ float hstS[HDIM];
  int g = blockIdx.x, t = threadIdx.x;
  int s = segs[g], e = segs[g+1];
  int lane = t & 63, w = t >> 6;
  if (t < HDIM) hstS[t] = qs[(size_t)g*768 + 512 + t];
  __syncthreads();
  float4 hq = *(const float4*)&hstS[lane*4];
  float m_run = -INFINITY, s_run = 0.f, racc = 0.f;
  for (int base = s; base < e; base += CK){
    int cnt = min(e - base, CK);
    for (int li = w; li < cnt; li += 4){
      short4 h4 = *(const short4*)&hb[(size_t)(base+li)*HDIM + lane*4];
      float v = h2f_(h4.x)*hq.x + h2f_(h4.y)*hq.y + h2f_(h4.z)*hq.z + h2f_(h4.w)*hq.w;
      for (int o=32; o; o>>=1) v += __shfl_down(v, o);
      if (lane==0) en[li] = v;
    }
    __syncthreads();
    red[t] = (t < cnt) ? en[t] : -INFINITY;
    __syncthreads();
    for (int o=128;o>0;o>>=1){ if (t<o) red[t]=fmaxf(red[t],red[t+o]); __syncthreads(); }
    float nm = fmaxf(m_run, red[0]);
    __syncthreads();
    float ce = (t < cnt) ? expf(en[t]-nm) : 0.f;
    red[t] = ce; __syncthreads();
    for (int o=128;o>0;o>>=1){ if (t<o) red[t]+=red[t+o]; __syncthreads(); }
    float csum = red[0];
    __syncthreads();
    if (t < cnt) en[t] = ce;
    __syncthreads();
    float scale = (m_run == -INFINITY) ? 0.f : expf(m_run - nm);
    s_run = s_run*scale + csum;
    racc  = racc*scale;
    for (int j=0;j<cnt;j++)
      racc += en[j] * h2f_(hb[(size_t)(base+j)*HDIM + t]);
    m_run = nm;
    __syncthreads();
  }
  float r = racc / (s_run + 1e-16f);
  size_t o = (size_t)g*768 + 256 + t;
  qs[o] = r;
  qsh[o] = f2h_(r);
}

// ---------------- fused classifier ----------------
__global__ void classifier_kernel(const float* __restrict__ qs,
   const float* __restrict__ cW1, const float* __restrict__ csc1, const float* __restrict__ csh1,
   const float* __restrict__ cW2, const float* __restrict__ csc2, const float* __restrict__ csh2,
   const float* __restrict__ cW3, const float* __restrict__ cb3, float* __restrict__ out){
  __shared__ float sq[512];
  __shared__ float so1[256];
  __shared__ float so2[128];
  __shared__ float fr[256];
  int g = blockIdx.x, t = threadIdx.x;
  sq[t]     = qs[(size_t)g*768 + t];
  sq[t+256] = qs[(size_t)g*768 + 256 + t];
  __syncthreads();
  float acc = 0.f;
  for (int k=0;k<512;k++) acc += sq[k]*cW1[(size_t)k*256 + t];
  so1[t] = fmaxf(acc*csc1[t]+csh1[t], 0.f);
  __syncthreads();
  if (t < 128){
    float a2 = 0.f;
    for (int k=0;k<256;k++) a2 += so1[k]*cW2[(size_t)k*128 + t];
    so2[t] = fmaxf(a2*csc2[t]+csh2[t], 0.f);
  }
  __syncthreads();
  fr[t] = (t<128) ? so2[t]*cW3[t] : 0.f;
  __syncthreads();
  for (int o=128;o>0;o>>=1){ if (t<o) fr[t]+=fr[t+o]; __syncthreads(); }
  if (t==0) out[g] = fr[0] + cb3[0];
}

// ---------------- host ----------------
extern "C" void kernel_launch(void* const* d_in, const int* in_sizes, int n_in,
                              void* d_out, int out_size, void* d_ws, size_t ws_size,
                              hipStream_t stream){
  const float* x         = (const float*)d_in[0];
  const float* edge_attr = (const float*)d_in[1];
  const int*   edge_idx  = (const int*)  d_in[2];
  const int*   batch     = (const int*)  d_in[3];
  const float* atom_W    = (const float*)d_in[4];
  const float* atom_b    = (const float*)d_in[5];
  const float* bond_W    = (const float*)d_in[6];
  const float* bond_b    = (const float*)d_in[7];
  const float* eps       = (const float*)d_in[8];
  const float* W1        = (const float*)d_in[9];
  const float* b1        = (const float*)d_in[10];
  const float* bn1_g     = (const float*)d_in[11];
  const float* bn1_b     = (const float*)d_in[12];
  const float* bn1_m     = (const float*)d_in[13];
  const float* bn1_v     = (const float*)d_in[14];
  const float* W2        = (const float*)d_in[15];
  const float* b2        = (const float*)d_in[16];
  const float* bn_g      = (const float*)d_in[17];
  const float* bn_b      = (const float*)d_in[18];
  const float* bn_m      = (const float*)d_in[19];
  const float* bn_v      = (const float*)d_in[20];
  const float* lstm_Wih  = (const float*)d_in[21];
  const float* lstm_Whh  = (const float*)d_in[22];
  const float* lstm_bih  = (const float*)d_in[23];
  const float* lstm_bhh  = (const float*)d_in[24];
  const float* cW1       = (const float*)d_in[25];
  const float* cb1       = (const float*)d_in[26];
  const float* cbn1_g    = (const float*)d_in[27];
  const float* cbn1_b    = (const float*)d_in[28];
  const float* cbn1_m    = (const float*)d_in[29];
  const float* cbn1_v    = (const float*)d_in[30];
  const float* cW2       = (const float*)d_in[31];
  const float* cb2       = (const float*)d_in[32];
  const float* cbn2_g    = (const float*)d_in[33];
  const float* cbn2_b    = (const float*)d_in[34];
  const float* cbn2_m    = (const float*)d_in[35];
  const float* cbn2_v    = (const float*)d_in[36];
  const float* cW3       = (const float*)d_in[37];
  const float* cb3       = (const float*)d_in[38];

  const int* src = edge_idx;
  const int* dst = edge_idx + N_EDGES;

  char* ws = (char*)d_ws;
  size_t off = 0;
  auto alloc = [&](size_t bytes)->void*{
    void* p = ws + off; off += (bytes + 255) & ~(size_t)255; return p;
  };
  short* hb0     = (short*)alloc((size_t)N_NODES*HDIM*2);     //  51.2 MB fp16 h master
  short* hb1     = (short*)alloc((size_t)N_NODES*HDIM*2);     //  51.2 MB fp16 h master
  int*   row_ptr = (int*)  alloc((size_t)(N_NODES+1)*4);
  int*   cursor  = (int*)  alloc((size_t)N_NODES*4);
  int*   s_eid   = (int*)  alloc((size_t)N_EDGES*4);
  int*   segs    = (int*)  alloc((size_t)(NB+1)*4);
  int*   s_src   = (int*)  alloc((size_t)N_EDGES*4);
  short* eah2    = (short*)alloc((size_t)N_EDGES*24*2);       //  19.2 MB
  short* bWh     = (short*)alloc((size_t)FBOND*HDIM*2);
  short* bbh     = (short*)alloc((size_t)HDIM*2);
  short* W1p     = (short*)alloc((size_t)NLAY*HDIM*2*HDIM*2); //  2.62 MB
  short* W2p     = (short*)alloc((size_t)NLAY*HDIM*2*HDIM*2); //  2.62 MB
  float* sc1     = (float*)alloc(NLAY*512*4);
  float* sh1     = (float*)alloc(NLAY*512*4);
  float* sc2     = (float*)alloc(NLAY*256*4);
  float* sh2     = (float*)alloc(NLAY*256*4);
  float* csc1    = (float*)alloc(256*4);
  float* csh1    = (float*)alloc(256*4);
  float* csc2    = (float*)alloc(128*4);
  float* csh2    = (float*)alloc(128*4);

  if (off >= ws_size){
    sentinel_kernel<<<(out_size+255)/256, 256, 0, stream>>>((float*)d_out, out_size);
    return;
  }

  // Set2Set scratch aliases hb0 (dead after layer 4 consumed it; final h in hb1).
  char*  zb      = (char*)(void*)hb0;
  float* gates   = (float*)zb;                          // 16.78 MB
  float* qs      = (float*)(zb + 16777216);             // 12.58 MB
  float* cst     = (float*)(zb + 29360128);             //  4.19 MB
  short* qsh     = (short*)(zb + 33554432);             //  6.29 MB
  short* Wcp     = (short*)(zb + 39845888);             //  1.57 MB
  float* bias_c  = (float*)(zb + 41418752);             //  4 KB

  // ---- prep: fold BN+bias, pack weights ----
  fold_kernel<<<(NLAY*512+NLAY*256+256+128+255)/256, 256, 0, stream>>>(
      b1, bn1_g, bn1_b, bn1_m, bn1_v,
      b2, bn_g,  bn_b,  bn_m,  bn_v,
      cb1, cbn1_g, cbn1_b, cbn1_m, cbn1_v,
      cb2, cbn2_g, cbn2_b, cbn2_m, cbn2_v,
      sc1, sh1, sc2, sh2, csc1, csh1, csc2, csh2);
  bondpack_kernel<<<(FBOND*HDIM+255)/256, 256, 0, stream>>>(bond_W, bond_b, bWh, bbh);
  for (int l=0; l<NLAY; l++){
    packB_kernel<<<(HDIM*2*HDIM)/256, 256, 0, stream>>>(
        W1 + (size_t)l*HDIM*2*HDIM, W1p + (size_t)l*HDIM*2*HDIM, HDIM, 2*HDIM);
    packB_kernel<<<(HDIM*2*HDIM)/256, 256, 0, stream>>>(
        W2 + (size_t)l*HDIM*2*HDIM, W2p + (size_t)l*HDIM*2*HDIM, 2*HDIM, HDIM);
  }

  // ---- embeddings (hb0 fp16 master) ----
  atom_embed_kernel<<<N_NODES/8, 256, 0, stream>>>(x, atom_W, atom_b, hb0);

  // ---- CSR by dst + batch segment starts + edge reorder ----
  hipMemsetAsync(cursor, 0, (size_t)N_NODES*4, stream);
  count_kernel<<<(N_EDGES+255)/256, 256, 0, stream>>>(dst, cursor, N_EDGES);
  scan_kernel<<<1, 1024, 0, stream>>>(cursor, row_ptr, N_NODES);
  hipMemcpyAsync(cursor, row_ptr, (size_t)N_NODES*4, hipMemcpyDeviceToDevice, stream);
  fill_kernel<<<(N_EDGES+255)/256, 256, 0, stream>>>(dst, cursor, s_eid, N_EDGES);
  segstart_kernel<<<(NB+256)/256, 256, 0, stream>>>(batch, segs, N_NODES, NB);
  reorder_kernel<<<(N_EDGES+255)/256, 256, 0, stream>>>(s_eid, src, edge_attr, s_src, eah2, N_EDGES);

  // ---- GINE layers: fused, fp16 h ping-pong ----
  const int gx = N_NODES/32;   // 3125, exact
  for (int l=0; l<NLAY; l++){
    const short* hbin = (l&1) ? hb1 : hb0;
    short*       hbo  = (l&1) ? hb0 : hb1;
    gine_layer_kernel<<<gx, 512, 0, stream>>>(
        hbin, hbo, bWh, bbh, s_src, eah2, row_ptr, eps, l,
        W1p + (size_t)l*HDIM*2*HDIM, W2p + (size_t)l*HDIM*2*HDIM,
        sc1 + l*512, sh1 + l*512, sc2 + l*256, sh2 + l*256);
  }
  const short* hf = hb1;   // NLAY=5 (odd) -> final h in hb1

  // ---- Set2Set (scratch aliases hb0, now dead) ----
  packWcat_kernel<<<(768*1024+255)/256, 256, 0, stream>>>(lstm_Wih, lstm_Whh, lstm_bih, lstm_bhh,
                                                          Wcp, bias_c);
  hipMemsetAsync(qsh, 0, (size_t)NB*768*2, stream);
  hipMemsetAsync(cst, 0, (size_t)NB*HDIM*4, stream);
  for (int sstep=0; sstep<3; sstep++){
    gemm_mfma0<<<dim3(1024/128, NB/64), 256, 0, stream>>>(
        qsh, Wcp, NB, 1024, 768, bias_c, gates);
    lstm_kernel<<<(NB*HDIM)/256, 256, 0, stream>>>(gates, cst, qs, qsh);
    attn_fused_kernel<<<NB, 256, 0, stream>>>(hf, qs, qsh, segs);
  }

  // ---- classifier ----
  classifier_kernel<<<NB, 256, 0, stream>>>(qs, cW1, csc1, csh1, cW2, csc2, csh2,
                                            cW3, cb3, (float*)d_out);
}

// Round 22
// 1309.162 us; speedup vs baseline: 1.1579x; 1.1579x over previous
//
#include <hip/hip_runtime.h>
#include <hip/hip_bf16.h>
#include <hip/hip_fp16.h>

#define N_NODES 100000
#define N_EDGES 400000
#define NB      4096
#define FAT     30
#define FBOND   11
#define HDIM    256
#define NLAY    5
#define CK      128

typedef short s8v  __attribute__((ext_vector_type(8)));
typedef float f32x4 __attribute__((ext_vector_type(4)));
typedef _Float16 f16x8 __attribute__((ext_vector_type(8)));
typedef unsigned int u32;

static __device__ __forceinline__ float sigmoidf_(float x){ return 1.0f/(1.0f+expf(-x)); }
static __device__ __forceinline__ float h2f_(short s){
  return __half2float(__ushort_as_half((unsigned short)s));
}
static __device__ __forceinline__ short f2h_(float f){
  return (short)__half_as_ushort(__float2half(f));
}
// packed fp16 ops via inline asm (avoids fp16/bf16 header overload ambiguity)
static __device__ __forceinline__ u32 pk_fma(u32 a, u32 b, u32 c){
  u32 r; asm("v_pk_fma_f16 %0, %1, %2, %3" : "=v"(r) : "v"(a), "v"(b), "v"(c)); return r;
}
static __device__ __forceinline__ u32 pk_add(u32 a, u32 b){
  u32 r; asm("v_pk_add_f16 %0, %1, %2" : "=v"(r) : "v"(a), "v"(b)); return r;
}
static __device__ __forceinline__ u32 pk_mul(u32 a, u32 b){
  u32 r; asm("v_pk_mul_f16 %0, %1, %2" : "=v"(r) : "v"(a), "v"(b)); return r;
}
static __device__ __forceinline__ u32 pk_max(u32 a, u32 b){
  u32 r; asm("v_pk_max_f16 %0, %1, %2" : "=v"(r) : "v"(a), "v"(b)); return r;
}

// ---------------- sentinel (ws too small diagnostic) ----------------
__global__ void sentinel_kernel(float* out, int n){
  int i = blockIdx.x*256 + threadIdx.x;
  if (i < n) out[i] = 12345.0f;
}

// ---------------- atom embedding: hb0 fp16 master ----------------
__global__ void atom_embed_kernel(const float* __restrict__ x, const float* __restrict__ W,
                                  const float* __restrict__ b, short* __restrict__ hb0){
  __shared__ float xs[8][FAT];
  int n0 = blockIdx.x * 8;
  int t = threadIdx.x;
  if (t < 8*FAT) xs[t/FAT][t%FAT] = x[(size_t)(n0 + t/FAT)*FAT + t%FAT];
  __syncthreads();
  int c = t;
  float acc[8];
  float bias = b[c];
  #pragma unroll
  for (int r=0;r<8;r++) acc[r]=bias;
  #pragma unroll
  for (int k=0;k<FAT;k++){
    float w = W[k*HDIM + c];
    #pragma unroll
    for (int r=0;r<8;r++) acc[r] += xs[r][k]*w;
  }
  #pragma unroll
  for (int r=0;r<8;r++)
    hb0[(size_t)(n0+r)*HDIM + c] = f2h_(acc[r]);
}

// ---------------- CSR build over dst ----------------
__global__ void count_kernel(const int* __restrict__ dst, int* __restrict__ counts, int E){
  int e = blockIdx.x*blockDim.x + threadIdx.x;
  if (e < E) atomicAdd(&counts[dst[e]], 1);
}

__global__ void scan_kernel(const int* __restrict__ counts, int* __restrict__ row_ptr, int n){
  __shared__ int part[1024];
  int t = threadIdx.x;
  int chunk = (n + 1023) >> 10;
  int s = t*chunk, e2 = min(s+chunk, n);
  int sum = 0;
  for (int i=s;i<e2;i++) sum += counts[i];
  part[t] = sum; __syncthreads();
  for (int off=1; off<1024; off<<=1){
    int v = (t>=off) ? part[t-off] : 0;
    __syncthreads();
    part[t] += v;
    __syncthreads();
  }
  int run = part[t]-sum;
  for (int i=s;i<e2;i++){ row_ptr[i]=run; run+=counts[i]; }
  if (e2==n && s<=n) row_ptr[n]=run;
}

__global__ void fill_kernel(const int* __restrict__ dst, int* __restrict__ cursor,
                            int* __restrict__ sorted_eid, int E){
  int e = blockIdx.x*blockDim.x + threadIdx.x;
  if (e < E){ int pos = atomicAdd(&cursor[dst[e]],1); sorted_eid[pos]=e; }
}

__global__ void segstart_kernel(const int* __restrict__ batch, int* __restrict__ segs, int n, int nb){
  int g = blockIdx.x*blockDim.x + threadIdx.x;
  if (g > nb) return;
  int lo=0, hi=n;
  while (lo<hi){ int mid=(lo+hi)>>1; if (batch[mid] < g) lo=mid+1; else hi=mid; }
  segs[g]=lo;
}

// ---------------- one-time edge reorder: linear src + broadcast-fp16 edge_attr ------
__global__ void reorder_kernel(const int* __restrict__ s_eid, const int* __restrict__ src,
                               const float* __restrict__ ea,
                               int* __restrict__ s_src, short* __restrict__ eah2, int E){
  int i = blockIdx.x*256 + threadIdx.x;
  if (i >= E) return;
  int eid = s_eid[i];
  s_src[i] = src[eid];
  const float* a = ea + (size_t)eid*FBOND;
  short* o = eah2 + (size_t)i*24;
  #pragma unroll
  for (int k=0;k<FBOND;k++){
    short hv = f2h_(a[k]);
    o[2*k]   = hv;
    o[2*k+1] = hv;
  }
  o[22] = 0; o[23] = 0;
}

// ---------------- pack bond weights/bias to fp16 ----------------
__global__ void bondpack_kernel(const float* __restrict__ bW, const float* __restrict__ bb,
                                short* __restrict__ bWh, short* __restrict__ bbh){
  int idx = blockIdx.x*256 + threadIdx.x;
  if (idx < FBOND*HDIM) bWh[idx] = f2h_(bW[idx]);
  if (idx < HDIM)       bbh[idx] = f2h_(bb[idx]);
}

// ---------------- pack weights into MFMA B-fragment layout, single fp16 -------------
__global__ void packB_kernel(const float* __restrict__ B, short* __restrict__ Bp, int K, int N){
  int idx = blockIdx.x*256 + threadIdx.x;
  if (idx >= K*N) return;
  int b    = idx & 7;
  int lane = (idx >> 3) & 63;
  int t2   = idx >> 9;
  int KT   = K >> 5;
  int kt   = t2 % KT, nt = t2 / KT;
  int k = kt*32 + ((lane>>4)<<3) + b;
  int n = nt*16 + (lane&15);
  Bp[idx] = f2h_(B[(size_t)k*N + n]);
}

// ---------------- pack LSTM [Wih|Whh]^T (K=768, N=1024) + bias, fp16 --------
__global__ void packWcat_kernel(const float* __restrict__ Wih, const float* __restrict__ Whh,
                                const float* __restrict__ bih, const float* __restrict__ bhh,
                                short* __restrict__ Wcp, float* __restrict__ bias_c){
  int idx = blockIdx.x*256 + threadIdx.x;
  if (idx < 1024) bias_c[idx] = bih[idx] + bhh[idx];
  if (idx >= 768*1024) return;
  int b    = idx & 7;
  int lane = (idx >> 3) & 63;
  int t2   = idx >> 9;
  const int KT = 24;
  int kt   = t2 % KT, nt = t2 / KT;
  int k = kt*32 + ((lane>>4)<<3) + b;
  int n = nt*16 + (lane&15);
  float w = (k < 512) ? Wih[(size_t)n*512 + k] : Whh[(size_t)n*256 + (k-512)];
  Wcp[idx] = f2h_(w);
}

// ---------------- fully fused GINE layer (fp16 master, packed-fp16 messages) --------
// 32 nodes/block, 512 threads. LDS 50.7 KB -> 3 blocks/CU: the proven optimum
// (r20). 4 blocks/CU (r21) inflated FETCH+WRITE 1.6-4x via cache churn; 2 blocks
// (r18) under-fed the latency-bound gather stream.
__launch_bounds__(512, 6)
__global__ void gine_layer_kernel(
    const short* __restrict__ hbin, short* __restrict__ hbout,
    const short* __restrict__ bWh, const short* __restrict__ bbh,
    const int* __restrict__ s_src, const short* __restrict__ eah2,
    const int* __restrict__ row_ptr, const float* __restrict__ eps, int layer,
    const short* __restrict__ B1p, const short* __restrict__ B2p,
    const float* __restrict__ sc1v, const float* __restrict__ sh1v,
    const float* __restrict__ sc2v, const float* __restrict__ sh2v){
  __shared__ short smem[25344];        // 50.7 KB -> 3 blocks/CU
  short* sZ  = smem;                   // [32][264] fp16
  short* sC1 = smem;                   // [32][520] fp16 (aliases z after GEMM1)
  float* sOut = (float*)smem;          // [32][264] fp32 (aliases c1 after GEMM2)
  short* sH  = smem + 16896;           // [32][264] fp16 own-row h (persistent)
  int t = threadIdx.x;
  int lane = t & 63, wid = t >> 6;
  int lrow = lane & 15, lk8 = (lane>>4)<<3, drow0 = (lane>>4)<<2;
  int m0 = blockIdx.x * 32;
  int c0 = lane*4;

  // ---- phase 1: message pass, packed fp16 (inline-asm VOP3P) ----
  {
    u32 w2[FBOND][2];
    #pragma unroll
    for (int k=0;k<FBOND;k++){
      w2[k][0] = *(const u32*)&bWh[k*HDIM + c0];
      w2[k][1] = *(const u32*)&bWh[k*HDIM + c0 + 2];
    }
    u32 bbA = *(const u32*)&bbh[c0];
    u32 bbB = *(const u32*)&bbh[c0 + 2];
    unsigned short eh = (unsigned short)f2h_(1.0f + eps[layer]);
    u32 eps2 = ((u32)eh << 16) | eh;
    for (int nn=0; nn<4; ++nn){
      int nl = wid*4 + nn;
      int node = m0 + nl;
      short4 hself = *(const short4*)&hbin[(size_t)node*HDIM + c0];
      *(short4*)&sH[nl*264 + c0] = hself;       // stage residual source
      u32 hs0 = *(u32*)&hself.x;
      u32 hs1 = *(u32*)&hself.z;
      u32 acc0 = pk_mul(eps2, hs0);
      u32 acc1 = pk_mul(eps2, hs1);
      int s = row_ptr[node], e = row_ptr[node+1];
      u32 hc0 = 0u, hc1 = 0u;
      if (s < e){
        short4 g4 = *(const short4*)&hbin[(size_t)s_src[s]*HDIM + c0];
        hc0 = *(u32*)&g4.x; hc1 = *(u32*)&g4.z;
      }
      for (int idx=s; idx<e; idx++){
        u32 hn0 = hc0, hn1 = hc1;
        if (idx+1 < e){
          short4 g4 = *(const short4*)&hbin[(size_t)s_src[idx+1]*HDIM + c0];
          hn0 = *(u32*)&g4.x; hn1 = *(u32*)&g4.z;
        }
        const u32* ap = (const u32*)(eah2 + (size_t)idx*24);
        u32 e0 = bbA, e1 = bbB;
        #pragma unroll
        for (int k=0;k<FBOND;k++){
          u32 a = ap[k];
          e0 = pk_fma(a, w2[k][0], e0);
          e1 = pk_fma(a, w2[k][1], e1);
        }
        e0 = pk_max(pk_add(hc0, e0), 0u);
        e1 = pk_max(pk_add(hc1, e1), 0u);
        acc0 = pk_add(acc0, e0);
        acc1 = pk_add(acc1, e1);
        hc0 = hn0; hc1 = hn1;
      }
      short4 zz;
      *(u32*)&zz.x = acc0;
      *(u32*)&zz.z = acc1;
      *(short4*)&sZ[nl*264 + c0] = zz;
    }
  }
  __syncthreads();

  // ---- phase 2: GEMM1, wave computes c1 cols [wid*64, +64), rows 0..31 ----
  f32x4 acc1g[2][4];
  #pragma unroll
  for (int i=0;i<2;i++)
    #pragma unroll
    for (int j=0;j<4;j++) acc1g[i][j] = (f32x4){0.f,0.f,0.f,0.f};
  size_t b1base = (size_t)wid*16384 + lane*8;          // nt = wid*4+nf, KT=8
  for (int kt=0; kt<8; ++kt){
    f16x8 bv[4];
    #pragma unroll
    for (int nf=0;nf<4;nf++)
      bv[nf] = *(const f16x8*)(B1p + b1base + ((size_t)nf*8 + kt)*512);
    #pragma unroll
    for (int mf=0;mf<2;mf++){
      int rsh = (mf*16 + lrow)*264 + kt*32 + lk8;
      f16x8 a = *(const f16x8*)&sZ[rsh];
      #pragma unroll
      for (int nf=0;nf<4;nf++)
        acc1g[mf][nf] = __builtin_amdgcn_mfma_f32_16x16x32_f16(a, bv[nf], acc1g[mf][nf],0,0,0);
    }
  }
  __syncthreads();   // all waves done reading z

  // ---- phase 3: write c1 = relu(bn1(.)) fp16 into LDS ----
  #pragma unroll
  for (int nf=0;nf<4;nf++){
    int col = wid*64 + nf*16 + lrow;
    float scv = sc1v[col], shv = sh1v[col];
    #pragma unroll
    for (int mf=0;mf<2;mf++){
      int row = mf*16 + drow0;
      #pragma unroll
      for (int r=0;r<4;r++){
        float v = fmaxf(acc1g[mf][nf][r]*scv + shv, 0.f);
        sC1[(row+r)*520 + col] = f2h_(v);
      }
    }
  }
  __syncthreads();

  // ---- phase 4: GEMM2, wave computes out cols [wid*32, +32), K=512 ----
  f32x4 acc2[2][2];
  #pragma unroll
  for (int i=0;i<2;i++)
    #pragma unroll
    for (int j=0;j<2;j++) acc2[i][j] = (f32x4){0.f,0.f,0.f,0.f};
  size_t b2base = (size_t)wid*16384 + lane*8;          // nt2 = wid*2+nf, KT2=16
  for (int kt=0; kt<16; ++kt){
    f16x8 b0 = *(const f16x8*)(B2p + b2base + (size_t)kt*512);
    f16x8 b1 = *(const f16x8*)(B2p + b2base + (size_t)(16+kt)*512);
    #pragma unroll
    for (int mf=0;mf<2;mf++){
      int rsh = (mf*16 + lrow)*520 + kt*32 + lk8;
      f16x8 a = *(const f16x8*)&sC1[rsh];
      acc2[mf][0] = __builtin_amdgcn_mfma_f32_16x16x32_f16(a, b0, acc2[mf][0],0,0,0);
      acc2[mf][1] = __builtin_amdgcn_mfma_f32_16x16x32_f16(a, b1, acc2[mf][1],0,0,0);
    }
  }
  __syncthreads();   // all waves done reading c1

  // ---- phase 5a: stage relu(bn2(.)) fp32 into LDS (aliases c1) ----
  #pragma unroll
  for (int nf=0;nf<2;nf++){
    int col = wid*32 + nf*16 + lrow;
    float scv = sc2v[col], shv = sh2v[col];
    #pragma unroll
    for (int mf=0;mf<2;mf++){
      #pragma unroll
      for (int r=0;r<4;r++){
        int rr = mf*16 + drow0 + r;
        sOut[rr*264 + col] = fmaxf(acc2[mf][nf][r]*scv + shv, 0.f);
      }
    }
  }
  __syncthreads();

  // ---- phase 5b: coalesced hbout = fp16(out + h_old) (h_old from sH) ----
  {
    int row = t >> 4, cs = (t & 15) * 16;
    int grow = m0 + row;
    const float* op = &sOut[row*264 + cs];
    const short* hp = &sH[row*264 + cs];
    s8v o0, o1;
    #pragma unroll
    for (int i=0;i<8;i++){
      o0[i] = f2h_(op[i]   + h2f_(hp[i]));
      o1[i] = f2h_(op[8+i] + h2f_(hp[8+i]));
    }
    short* mp = hbout + (size_t)grow*HDIM + cs;
    *(s8v*)(mp)     = o0;
    *(s8v*)(mp + 8) = o1;
  }
}

// ---------------- fp16 MFMA GEMM (LSTM gates), LDS-staged A ----------------
__launch_bounds__(256)
__global__ void gemm_mfma0(const short* __restrict__ Ap, const short* __restrict__ Bp,
                           int M, int N, int K,
                           const float* __restrict__ sh, float* __restrict__ Cf){
  __shared__ short As[2][64*72];
  int t    = threadIdx.x;
  int lane = t & 63;
  int wid  = t >> 6;
  int m0 = blockIdx.y * 64;
  int n0 = blockIdx.x * 128 + wid * 32;
  int lrow = lane & 15;
  int lk8  = (lane >> 4) << 3;
  int KT = K >> 5;
  int NT = K >> 6;

  f32x4 acc[4][2];
  #pragma unroll
  for (int i=0;i<4;i++)
    #pragma unroll
    for (int j=0;j<2;j++) acc[i][j] = (f32x4){0.f,0.f,0.f,0.f};

  int r0 = t >> 3, c8 = t & 7;
  int gr0 = min(m0 + r0,      M-1);
  int gr1 = min(m0 + r0 + 32, M-1);
  const short* pa0 = Ap + (size_t)gr0*K + c8*8;
  const short* pa1 = Ap + (size_t)gr1*K + c8*8;
  int wsh0 = r0*72 + c8*8;
  int wsh1 = (r0+32)*72 + c8*8;

  size_t boff = ((size_t)(n0 >> 4) * KT) * 512 + lane*8;

  s8v v0 = *(const s8v*)(pa0);
  s8v v1 = *(const s8v*)(pa1);
  *(s8v*)&As[0][wsh0] = v0;  *(s8v*)&As[0][wsh1] = v1;
  __syncthreads();

  for (int st=0; st<NT; ++st){
    int cur = st & 1;
    if (st+1 < NT){
      int ko = (st+1)*64;
      v0 = *(const s8v*)(pa0 + ko);
      v1 = *(const s8v*)(pa1 + ko);
    }
    #pragma unroll
    for (int ktl=0; ktl<2; ++ktl){
      int kt = st*2 + ktl;
      f16x8 b0 = *(const f16x8*)(Bp + boff + (size_t)kt*512);
      f16x8 b1 = *(const f16x8*)(Bp + boff + (size_t)(KT + kt)*512);
      int ksh = ktl*32 + lk8;
      #pragma unroll
      for (int mf=0; mf<4; ++mf){
        int rsh = (mf*16 + lrow)*72 + ksh;
        f16x8 a = *(const f16x8*)&As[cur][rsh];
        acc[mf][0] = __builtin_amdgcn_mfma_f32_16x16x32_f16(a, b0, acc[mf][0], 0,0,0);
        acc[mf][1] = __builtin_amdgcn_mfma_f32_16x16x32_f16(a, b1, acc[mf][1], 0,0,0);
      }
    }
    if (st+1 < NT){
      int nxt = cur ^ 1;
      *(s8v*)&As[nxt][wsh0] = v0;  *(s8v*)&As[nxt][wsh1] = v1;
    }
    __syncthreads();
  }

  int drow0 = (lane >> 4) * 4;
  #pragma unroll
  for (int nf=0; nf<2; nf++){
    int col = n0 + nf*16 + lrow;
    float shv = sh[col];
    #pragma unroll
    for (int mf=0; mf<4; mf++){
      #pragma unroll
      for (int r=0; r<4; r++){
        int row = m0 + mf*16 + drow0 + r;
        if (row < M) Cf[(size_t)row*N + col] = acc[mf][nf][r] + shv;
      }
    }
  }
}

// ---------------- BN fold ----------------
__global__ void fold_kernel(
  const float* __restrict__ b1,  const float* __restrict__ g1,  const float* __restrict__ bb1,
  const float* __restrict__ m1,  const float* __restrict__ v1,
  const float* __restrict__ b2,  const float* __restrict__ g2,  const float* __restrict__ bb2,
  const float* __restrict__ m2,  const float* __restrict__ v2,
  const float* __restrict__ cb1, const float* __restrict__ cg1, const float* __restrict__ cbb1,
  const float* __restrict__ cm1, const float* __restrict__ cv1,
  const float* __restrict__ cb2, const float* __restrict__ cg2, const float* __restrict__ cbb2,
  const float* __restrict__ cm2, const float* __restrict__ cv2,
  float* __restrict__ sc1, float* __restrict__ sh1,
  float* __restrict__ sc2, float* __restrict__ sh2,
  float* __restrict__ csc1, float* __restrict__ csh1,
  float* __restrict__ csc2, float* __restrict__ csh2){
  int idx = blockIdx.x*256 + threadIdx.x;
  const int n1 = NLAY*512, n2 = NLAY*256;
  if (idx < n1){
    float s = g1[idx]*rsqrtf(v1[idx]+1e-5f);
    sc1[idx]=s; sh1[idx]=(b1[idx]-m1[idx])*s + bb1[idx];
  } else if (idx < n1+n2){
    int i = idx-n1;
    float s = g2[i]*rsqrtf(v2[i]+1e-5f);
    sc2[i]=s; sh2[i]=(b2[i]-m2[i])*s + bb2[i];
  } else if (idx < n1+n2+256){
    int i = idx-n1-n2;
    float s = cg1[i]*rsqrtf(cv1[i]+1e-5f);
    csc1[i]=s; csh1[i]=(cb1[i]-cm1[i])*s + cbb1[i];
  } else if (idx < n1+n2+256+128){
    int i = idx-n1-n2-256;
    float s = cg2[i]*rsqrtf(cv2[i]+1e-5f);
    csc2[i]=s; csh2[i]=(cb2[i]-cm2[i])*s + cbb2[i];
  }
}

// ---------------- LSTM pointwise (writes q/hst fp32 + fp16 mirror) ----------------
__global__ void lstm_kernel(const float* __restrict__ gates, float* __restrict__ cst,
                            float* __restrict__ qs, short* __restrict__ qsh){
  int idx = blockIdx.x*256 + threadIdx.x;
  int b = idx >> 8, j = idx & 255;
  const float* g = &gates[(size_t)b*1024];
  float ig = sigmoidf_(g[j]);
  float fg = sigmoidf_(g[j+256]);
  float gg = tanhf(g[j+512]);
  float og = sigmoidf_(g[j+768]);
  float c  = fg*cst[idx] + ig*gg;
  float hv = og*tanhf(c);
  cst[idx] = c;
  size_t base = (size_t)b*768;
  qs[base + j]       = hv;
  qs[base + 512 + j] = hv;
  short hh = f2h_(hv);
  qsh[base + j] = hh;
  qsh[base + 512 + j] = hh;
}

// ---------------- fused attention (fp16 h): ener + softmax + weighted r ----------------
__global__ void attn_fused_kernel(const short* __restrict__ hb, float* __restrict__ qs,
                                  short* __restrict__ qsh, const int* __restrict__ segs){
  __shared__ float en[CK];
  __shared__ float red[256];
  __shared__ float hstS[HDIM];
  int g = blockIdx.x, t = threadIdx.x;
  int s = segs[g], e = segs[g+1];
  int lane = t & 63, w = t >> 6;
  if (t < HDIM) hstS[t] = qs[(size_t)g*768 + 512 + t];
  __syncthreads();
  float4 hq = *(const float4*)&hstS[lane*4];
  float m_run = -INFINITY, s_run = 0.f, racc = 0.f;
  for (int base = s; base < e; base += CK){
    int cnt = min(e - base, CK);
    for (int li = w; li < cnt; li += 4){
      short4 h4 = *(const short4*)&hb[(size_t)(base+li)*HDIM + lane*4];
      float v = h2f_(h4.x)*hq.x + h2f_(h4.y)*hq.y + h2f_(h4.z)*hq.z + h2f_(h4.w)*hq.w;
      for (int o=32; o; o>>=1) v += __shfl_down(v, o);
      if (lane==0) en[li] = v;
    }
    __syncthreads();
    red[t] = (t < cnt) ? en[t] : -INFINITY;
    __syncthreads();
    for (int o=128;o>0;o>>=1){ if (t<o) red[t]=fmaxf(red[t],red[t+o]); __syncthreads(); }
    float nm = fmaxf(m_run, red[0]);
    __syncthreads();
    float ce = (t < cnt) ? expf(en[t]-nm) : 0.f;
    red[t] = ce; __syncthreads();
    for (int o=128;o>0;o>>=1){ if (t<o) red[t]+=red[t+o]; __syncthreads(); }
    float csum = red[0];
    __syncthreads();
    if (t < cnt) en[t] = ce;
    __syncthreads();
    float scale = (m_run == -INFINITY) ? 0.f : expf(m_run - nm);
    s_run = s_run*scale + csum;
    racc  = racc*scale;
    for (int j=0;j<cnt;j++)
      racc += en[j] * h2f_(hb[(size_t)(base+j)*HDIM + t]);
    m_run = nm;
    __syncthreads();
  }
  float r = racc / (s_run + 1e-16f);
  size_t o = (size_t)g*768 + 256 + t;
  qs[o] = r;
  qsh[o] = f2h_(r);
}

// ---------------- fused classifier ----------------
__global__ void classifier_kernel(const float* __restrict__ qs,
   const float* __restrict__ cW1, const float* __restrict__ csc1, const float* __restrict__ csh1,
   const float* __restrict__ cW2, const float* __restrict__ csc2, const float* __restrict__ csh2,
   const float* __restrict__ cW3, const float* __restrict__ cb3, float* __restrict__ out){
  __shared__ float sq[512];
  __shared__ float so1[256];
  __shared__ float so2[128];
  __shared__ float fr[256];
  int g = blockIdx.x, t = threadIdx.x;
  sq[t]     = qs[(size_t)g*768 + t];
  sq[t+256] = qs[(size_t)g*768 + 256 + t];
  __syncthreads();
  float acc = 0.f;
  for (int k=0;k<512;k++) acc += sq[k]*cW1[(size_t)k*256 + t];
  so1[t] = fmaxf(acc*csc1[t]+csh1[t], 0.f);
  __syncthreads();
  if (t < 128){
    float a2 = 0.f;
    for (int k=0;k<256;k++) a2 += so1[k]*cW2[(size_t)k*128 + t];
    so2[t] = fmaxf(a2*csc2[t]+csh2[t], 0.f);
  }
  __syncthreads();
  fr[t] = (t<128) ? so2[t]*cW3[t] : 0.f;
  __syncthreads();
  for (int o=128;o>0;o>>=1){ if (t<o) fr[t]+=fr[t+o]; __syncthreads(); }
  if (t==0) out[g] = fr[0] + cb3[0];
}

// ---------------- host ----------------
extern "C" void kernel_launch(void* const* d_in, const int* in_sizes, int n_in,
                              void* d_out, int out_size, void* d_ws, size_t ws_size,
                              hipStream_t stream){
  const float* x         = (const float*)d_in[0];
  const float* edge_attr = (const float*)d_in[1];
  const int*   edge_idx  = (const int*)  d_in[2];
  const int*   batch     = (const int*)  d_in[3];
  const float* atom_W    = (const float*)d_in[4];
  const float* atom_b    = (const float*)d_in[5];
  const float* bond_W    = (const float*)d_in[6];
  const float* bond_b    = (const float*)d_in[7];
  const float* eps       = (const float*)d_in[8];
  const float* W1        = (const float*)d_in[9];
  const float* b1        = (const float*)d_in[10];
  const float* bn1_g     = (const float*)d_in[11];
  const float* bn1_b     = (const float*)d_in[12];
  const float* bn1_m     = (const float*)d_in[13];
  const float* bn1_v     = (const float*)d_in[14];
  const float* W2        = (const float*)d_in[15];
  const float* b2        = (const float*)d_in[16];
  const float* bn_g      = (const float*)d_in[17];
  const float* bn_b      = (const float*)d_in[18];
  const float* bn_m      = (const float*)d_in[19];
  const float* bn_v      = (const float*)d_in[20];
  const float* lstm_Wih  = (const float*)d_in[21];
  const float* lstm_Whh  = (const float*)d_in[22];
  const float* lstm_bih  = (const float*)d_in[23];
  const float* lstm_bhh  = (const float*)d_in[24];
  const float* cW1       = (const float*)d_in[25];
  const float* cb1       = (const float*)d_in[26];
  const float* cbn1_g    = (const float*)d_in[27];
  const float* cbn1_b    = (const float*)d_in[28];
  const float* cbn1_m    = (const float*)d_in[29];
  const float* cbn1_v    = (const float*)d_in[30];
  const float* cW2       = (const float*)d_in[31];
  const float* cb2       = (const float*)d_in[32];
  const float* cbn2_g    = (const float*)d_in[33];
  const float* cbn2_b    = (const float*)d_in[34];
  const float* cbn2_m    = (const float*)d_in[35];
  const float* cbn2_v    = (const float*)d_in[36];
  const float* cW3       = (const float*)d_in[37];
  const float* cb3       = (const float*)d_in[38];

  const int* src = edge_idx;
  const int* dst = edge_idx + N_EDGES;

  char* ws = (char*)d_ws;
  size_t off = 0;
  auto alloc = [&](size_t bytes)->void*{
    void* p = ws + off; off += (bytes + 255) & ~(size_t)255; return p;
  };
  short* hb0     = (short*)alloc((size_t)N_NODES*HDIM*2);     //  51.2 MB fp16 h master
  short* hb1     = (short*)alloc((size_t)N_NODES*HDIM*2);     //  51.2 MB fp16 h master
  int*   row_ptr = (int*)  alloc((size_t)(N_NODES+1)*4);
  int*   cursor  = (int*)  alloc((size_t)N_NODES*4);
  int*   s_eid   = (int*)  alloc((size_t)N_EDGES*4);
  int*   segs    = (int*)  alloc((size_t)(NB+1)*4);
  int*   s_src   = (int*)  alloc((size_t)N_EDGES*4);
  short* eah2    = (short*)alloc((size_t)N_EDGES*24*2);       //  19.2 MB
  short* bWh     = (short*)alloc((size_t)FBOND*HDIM*2);
  short* bbh     = (short*)alloc((size_t)HDIM*2);
  short* W1p     = (short*)alloc((size_t)NLAY*HDIM*2*HDIM*2); //  2.62 MB
  short* W2p     = (short*)alloc((size_t)NLAY*HDIM*2*HDIM*2); //  2.62 MB
  float* sc1     = (float*)alloc(NLAY*512*4);
  float* sh1     = (float*)alloc(NLAY*512*4);
  float* sc2     = (float*)alloc(NLAY*256*4);
  float* sh2     = (float*)alloc(NLAY*256*4);
  float* csc1    = (float*)alloc(256*4);
  float* csh1    = (float*)alloc(256*4);
  float* csc2    = (float*)alloc(128*4);
  float* csh2    = (float*)alloc(128*4);

  if (off >= ws_size){
    sentinel_kernel<<<(out_size+255)/256, 256, 0, stream>>>((float*)d_out, out_size);
    return;
  }

  // Set2Set scratch aliases hb0 (dead after layer 4 consumed it; final h in hb1).
  char*  zb      = (char*)(void*)hb0;
  float* gates   = (float*)zb;                          // 16.78 MB
  float* qs      = (float*)(zb + 16777216);             // 12.58 MB
  float* cst     = (float*)(zb + 29360128);             //  4.19 MB
  short* qsh     = (short*)(zb + 33554432);             //  6.29 MB
  short* Wcp     = (short*)(zb + 39845888);             //  1.57 MB
  float* bias_c  = (float*)(zb + 41418752);             //  4 KB

  // ---- prep: fold BN+bias, pack weights ----
  fold_kernel<<<(NLAY*512+NLAY*256+256+128+255)/256, 256, 0, stream>>>(
      b1, bn1_g, bn1_b, bn1_m, bn1_v,
      b2, bn_g,  bn_b,  bn_m,  bn_v,
      cb1, cbn1_g, cbn1_b, cbn1_m, cbn1_v,
      cb2, cbn2_g, cbn2_b, cbn2_m, cbn2_v,
      sc1, sh1, sc2, sh2, csc1, csh1, csc2, csh2);
  bondpack_kernel<<<(FBOND*HDIM+255)/256, 256, 0, stream>>>(bond_W, bond_b, bWh, bbh);
  for (int l=0; l<NLAY; l++){
    packB_kernel<<<(HDIM*2*HDIM)/256, 256, 0, stream>>>(
        W1 + (size_t)l*HDIM*2*HDIM, W1p + (size_t)l*HDIM*2*HDIM, HDIM, 2*HDIM);
    packB_kernel<<<(HDIM*2*HDIM)/256, 256, 0, stream>>>(
        W2 + (size_t)l*HDIM*2*HDIM, W2p + (size_t)l*HDIM*2*HDIM, 2*HDIM, HDIM);
  }

  // ---- embeddings (hb0 fp16 master) ----
  atom_embed_kernel<<<N_NODES/8, 256, 0, stream>>>(x, atom_W, atom_b, hb0);

  // ---- CSR by dst + batch segment starts + edge reorder ----
  hipMemsetAsync(cursor, 0, (size_t)N_NODES*4, stream);
  count_kernel<<<(N_EDGES+255)/256, 256, 0, stream>>>(dst, cursor, N_EDGES);
  scan_kernel<<<1, 1024, 0, stream>>>(cursor, row_ptr, N_NODES);
  hipMemcpyAsync(cursor, row_ptr, (size_t)N_NODES*4, hipMemcpyDeviceToDevice, stream);
  fill_kernel<<<(N_EDGES+255)/256, 256, 0, stream>>>(dst, cursor, s_eid, N_EDGES);
  segstart_kernel<<<(NB+256)/256, 256, 0, stream>>>(batch, segs, N_NODES, NB);
  reorder_kernel<<<(N_EDGES+255)/256, 256, 0, stream>>>(s_eid, src, edge_attr, s_src, eah2, N_EDGES);

  // ---- GINE layers: fused, fp16 h ping-pong ----
  const int gx = N_NODES/32;   // 3125, exact
  for (int l=0; l<NLAY; l++){
    const short* hbin = (l&1) ? hb1 : hb0;
    short*       hbo  = (l&1) ? hb0 : hb1;
    gine_layer_kernel<<<gx, 512, 0, stream>>>(
        hbin, hbo, bWh, bbh, s_src, eah2, row_ptr, eps, l,
        W1p + (size_t)l*HDIM*2*HDIM, W2p + (size_t)l*HDIM*2*HDIM,
        sc1 + l*512, sh1 + l*512, sc2 + l*256, sh2 + l*256);
  }
  const short* hf = hb1;   // NLAY=5 (odd) -> final h in hb1

  // ---- Set2Set (scratch aliases hb0, now dead) ----
  packWcat_kernel<<<(768*1024+255)/256, 256, 0, stream>>>(lstm_Wih, lstm_Whh, lstm_bih, lstm_bhh,
                                                          Wcp, bias_c);
  hipMemsetAsync(qsh, 0, (size_t)NB*768*2, stream);
  hipMemsetAsync(cst, 0, (size_t)NB*HDIM*4, stream);
  for (int sstep=0; sstep<3; sstep++){
    gemm_mfma0<<<dim3(1024/128, NB/64), 256, 0, stream>>>(
        qsh, Wcp, NB, 1024, 768, bias_c, gates);
    lstm_kernel<<<(NB*HDIM)/256, 256, 0, stream>>>(gates, cst, qs, qsh);
    attn_fused_kernel<<<NB, 256, 0, stream>>>(hf, qs, qsh, segs);
  }

  // ---- classifier ----
  classifier_kernel<<<NB, 256, 0, stream>>>(qs, cW1, csc1, csh1, cW2, csc2, csh2,
                                            cW3, cb3, (float*)d_out);
}